// Round 4
// baseline (110.404 us; speedup 1.0000x reference)
//
#include <hip/hip_runtime.h>

#define BB   128
#define DD   1024
#define RR   36
#define PP   8
#define NNEG 16
#define PRR  4

typedef __bf16 bf16x8 __attribute__((ext_vector_type(8)));
typedef float f32x4 __attribute__((ext_vector_type(4)));

// ws float layout: [0]=obj [1]=attr [2]=rel [3]=comp [4]=sent ; [16..400)=diag[3][128]
// byte 4096+: bf16 feat fragments [b][nt(3)][ks(32)][lane(64)][8]
#define WS_DIAG 16
#define WSF_OFF_BYTES 4096
#define WSF_PER_B (3 * 32 * 64 * 8)  // bf16 elems per b
#define WSF_BYTES ((size_t)WSF_OFF_BYTES + (size_t)BB * WSF_PER_B * 2)

__global__ __launch_bounds__(64) void k_zero(float* __restrict__ ws) {
    int t = threadIdx.x;
    if (t < 8) ws[t] = 0.0f;
}

__global__ __launch_bounds__(64) void k_diag(const float* __restrict__ img,
                                             const float* __restrict__ sent,
                                             const float* __restrict__ comp,
                                             const float* __restrict__ rel,
                                             const int*   __restrict__ relidx,
                                             float* __restrict__ ws) {
    const int i = blockIdx.x, t = blockIdx.y, lane = threadIdx.x;
    const float* x;
    if (t == 0)      x = sent + (size_t)i * DD;
    else if (t == 1) x = comp + (size_t)i * DD;
    else             x = rel + ((size_t)i * PRR + relidx[i]) * DD;
    const float* a = img + (size_t)i * DD;
    float acc = 0.0f;
#pragma unroll
    for (int k = 0; k < 4; ++k) {
        float4 va = *reinterpret_cast<const float4*>(a + lane * 4 + k * 256);
        float4 vb = *reinterpret_cast<const float4*>(x + lane * 4 + k * 256);
        acc += va.x * vb.x + va.y * vb.y + va.z * vb.z + va.w * vb.w;
    }
#pragma unroll
    for (int off = 32; off > 0; off >>= 1) acc += __shfl_down(acc, off);
    if (lane == 0) ws[WS_DIAG + t * BB + i] = acc;
}

// scores tile (16x16) per block; grid (8,8,3); 256 threads = 16x16
__global__ __launch_bounds__(256) void k_contrastive(const float* __restrict__ img,
                                                     const float* __restrict__ sent,
                                                     const float* __restrict__ comp,
                                                     const float* __restrict__ rel,
                                                     const int*   __restrict__ relidx,
                                                     float* __restrict__ ws) {
    const int t  = blockIdx.z;
    const int i0 = blockIdx.y * 16, j0 = blockIdx.x * 16;
    const int tid = threadIdx.x, ty = tid >> 4, tx = tid & 15;
    __shared__ float As[16][68];
    __shared__ float Bs[16][68];
    __shared__ float red[4];

    const int j_row = j0 + ty;
    const float* brow;
    if (t == 0)      brow = sent + (size_t)j_row * DD;
    else if (t == 1) brow = comp + (size_t)j_row * DD;
    else             brow = rel + ((size_t)j_row * PRR + relidx[j_row]) * DD;
    const float* arow = img + (size_t)(i0 + ty) * DD;

    float acc = 0.0f;
    for (int kc = 0; kc < DD; kc += 64) {
        __syncthreads();
        float4 va = *reinterpret_cast<const float4*>(arow + kc + tx * 4);
        float4 vb = *reinterpret_cast<const float4*>(brow + kc + tx * 4);
        *reinterpret_cast<float4*>(&As[ty][tx * 4]) = va;
        *reinterpret_cast<float4*>(&Bs[ty][tx * 4]) = vb;
        __syncthreads();
#pragma unroll 8
        for (int d = 0; d < 64; ++d)
            acc += As[ty][d] * Bs[tx][d];
    }

    const int i = i0 + ty, j = j0 + tx;
    const float diag_i = ws[WS_DIAG + t * BB + i];
    const float diag_j = ws[WS_DIAG + t * BB + j];
    float contrib = 0.0f;
    if (i != j) {
        contrib = fmaxf(acc - diag_i, 0.0f);             // cost_s
        if (t < 2) contrib += fmaxf(acc - diag_j, 0.0f); // cost_im (not for rel)
    }
#pragma unroll
    for (int off = 32; off > 0; off >>= 1) contrib += __shfl_down(contrib, off);
    if ((tid & 63) == 0) red[tid >> 6] = contrib;
    __syncthreads();
    if (tid == 0) {
        const int slot = (t == 0) ? 4 : (t == 1) ? 3 : 2;  // sent/comp/rel
        atomicAdd(&ws[slot], red[0] + red[1] + red[2] + red[3]);
    }
}

// global_loss for rel: grid(512) = (b,p); 64 threads
__global__ __launch_bounds__(64) void k_globalrel(const float* __restrict__ img,
                                                  const float* __restrict__ rel,
                                                  const float* __restrict__ negrel,
                                                  float* __restrict__ ws) {
    const int blk = blockIdx.x, b = blk >> 2, p = blk & 3;
    const int lane = threadIdx.x;
    const float* a = img + (size_t)b * DD;
    float4 ir[4];
#pragma unroll
    for (int k = 0; k < 4; ++k)
        ir[k] = *reinterpret_cast<const float4*>(a + lane * 4 + k * 256);

    auto dotv = [&](const float* __restrict__ v) -> float {
        float acc = 0.0f;
#pragma unroll
        for (int k = 0; k < 4; ++k) {
            float4 w = *reinterpret_cast<const float4*>(v + lane * 4 + k * 256);
            acc += ir[k].x * w.x + ir[k].y * w.y + ir[k].z * w.z + ir[k].w * w.w;
        }
#pragma unroll
        for (int off = 32; off > 0; off >>= 1) acc += __shfl_xor(acc, off);
        return acc;
    };

    float pos = dotv(rel + ((size_t)b * PRR + p) * DD);
    float mx = -1e30f;
    const float* nb = negrel + ((size_t)b * PRR + p) * NNEG * DD;
    for (int n = 0; n < NNEG; ++n) mx = fmaxf(mx, dotv(nb + (size_t)n * DD));
    if (lane == 0) atomicAdd(&ws[2], fmaxf(mx - pos, 0.0f));
}

// Pre-convert feat to bf16 in MFMA B-fragment layout: [b][nt][ks][lane]x8,
// where lane encodes (col r = nt*16 + (lane&15), k-sub (lane>>4)*8).
__global__ __launch_bounds__(256) void k_featcvt(const float* __restrict__ feat,
                                                 __bf16* __restrict__ wsf) {
    const int b = blockIdx.x, nt = blockIdx.y, tid = threadIdx.x;
    const float* fb = feat + (size_t)b * RR * DD;
    __bf16* ob = wsf + (size_t)b * WSF_PER_B + (size_t)nt * 32 * 64 * 8;
    for (int i = tid; i < 32 * 64; i += 256) {
        const int ks = i >> 6, lane = i & 63;
        const int r = nt * 16 + (lane & 15);
        const int k0 = ks * 32 + (lane >> 4) * 8;
        bf16x8 w;
        if (r < RR) {
            float4 v0 = *reinterpret_cast<const float4*>(fb + (size_t)r * DD + k0);
            float4 v1 = *reinterpret_cast<const float4*>(fb + (size_t)r * DD + k0 + 4);
            w[0] = (__bf16)v0.x; w[1] = (__bf16)v0.y; w[2] = (__bf16)v0.z; w[3] = (__bf16)v0.w;
            w[4] = (__bf16)v1.x; w[5] = (__bf16)v1.y; w[6] = (__bf16)v1.z; w[7] = (__bf16)v1.w;
        } else {
#pragma unroll
            for (int j = 0; j < 8; ++j) w[j] = (__bf16)0.0f;
        }
        *reinterpret_cast<bf16x8*>(ob + (size_t)i * 8) = w;
    }
}

// local_loss via bf16 MFMA, no LDS, chunk-4 burst pipeline (28 loads in flight).
// grid (3 t, 128 b, 2 p-half); 256 threads = 4 waves; wave = p = z*4+wv.
#define CHUNK 4
template <bool WSFEAT>
__global__ __launch_bounds__(256, 3) void k_local4(const float* __restrict__ feat,
                                                   const float* __restrict__ obj,
                                                   const float* __restrict__ attr,
                                                   const float* __restrict__ nobj,
                                                   const float* __restrict__ nattrn,
                                                   const float* __restrict__ nattra,
                                                   const __bf16* __restrict__ wsf,
                                                   float* __restrict__ ws) {
    const int t = blockIdx.x;   // 0:obj 1:attr(n) 2:attr(a)
    const int b = blockIdx.y;
    const int tid = threadIdx.x;
    const int wv = tid >> 6;
    const int p = blockIdx.z * 4 + wv;
    const int lane = tid & 63;
    const int lrow = lane & 15;
    const int kgq = lane >> 4;          // k-sub-group, *8 for element offset

    const float* pos = (t == 0) ? obj : attr;
    const float* neg = (t == 0) ? nobj : (t == 1) ? nattrn : nattra;
    const float* posb = pos + ((size_t)b * PP + p) * DD + kgq * 8;
    const float* negb = neg + ((size_t)(b * PP + p) * NNEG + lrow) * DD + kgq * 8;
    const float* fb   = feat + (size_t)b * RR * DD;
    const __bf16* wfb = wsf + (size_t)b * WSF_PER_B + (size_t)lane * 8;

    f32x4 accn[3], accp[3];
#pragma unroll
    for (int nt = 0; nt < 3; ++nt) {
        accn[nt] = (f32x4){0.f, 0.f, 0.f, 0.f};
        accp[nt] = (f32x4){0.f, 0.f, 0.f, 0.f};
    }

    for (int c = 0; c < 32 / CHUNK; ++c) {
        float4 n0[CHUNK], n1[CHUNK], p0[CHUNK], p1[CHUNK];
        bf16x8 f[CHUNK][3];
        // burst-issue all loads of the chunk (28 independent 16B loads)
#pragma unroll
        for (int j = 0; j < CHUNK; ++j) {
            const int ks = c * CHUNK + j;
            const float* np = negb + ks * 32;
            n0[j] = *reinterpret_cast<const float4*>(np);
            n1[j] = *reinterpret_cast<const float4*>(np + 4);
            const float* pp = posb + ks * 32;
            p0[j] = *reinterpret_cast<const float4*>(pp);
            p1[j] = *reinterpret_cast<const float4*>(pp + 4);
            if (WSFEAT) {
#pragma unroll
                for (int nt = 0; nt < 3; ++nt)
                    f[j][nt] = *reinterpret_cast<const bf16x8*>(
                        wfb + ((size_t)(nt * 32 + ks)) * 512);
            } else {
#pragma unroll
                for (int nt = 0; nt < 3; ++nt) {
                    const int r = nt * 16 + lrow;
                    if (r < RR) {
                        const float* fp = fb + (size_t)r * DD + ks * 32 + kgq * 8;
                        float4 v0 = *reinterpret_cast<const float4*>(fp);
                        float4 v1 = *reinterpret_cast<const float4*>(fp + 4);
                        f[j][nt][0] = (__bf16)v0.x; f[j][nt][1] = (__bf16)v0.y;
                        f[j][nt][2] = (__bf16)v0.z; f[j][nt][3] = (__bf16)v0.w;
                        f[j][nt][4] = (__bf16)v1.x; f[j][nt][5] = (__bf16)v1.y;
                        f[j][nt][6] = (__bf16)v1.z; f[j][nt][7] = (__bf16)v1.w;
                    } else {
#pragma unroll
                        for (int q = 0; q < 8; ++q) f[j][nt][q] = (__bf16)0.0f;
                    }
                }
            }
        }
        // compute the chunk
#pragma unroll
        for (int j = 0; j < CHUNK; ++j) {
            bf16x8 an, ap;
            an[0] = (__bf16)n0[j].x; an[1] = (__bf16)n0[j].y;
            an[2] = (__bf16)n0[j].z; an[3] = (__bf16)n0[j].w;
            an[4] = (__bf16)n1[j].x; an[5] = (__bf16)n1[j].y;
            an[6] = (__bf16)n1[j].z; an[7] = (__bf16)n1[j].w;
            ap[0] = (__bf16)p0[j].x; ap[1] = (__bf16)p0[j].y;
            ap[2] = (__bf16)p0[j].z; ap[3] = (__bf16)p0[j].w;
            ap[4] = (__bf16)p1[j].x; ap[5] = (__bf16)p1[j].y;
            ap[6] = (__bf16)p1[j].z; ap[7] = (__bf16)p1[j].w;
#pragma unroll
            for (int nt = 0; nt < 3; ++nt) {
                accn[nt] = __builtin_amdgcn_mfma_f32_16x16x32_bf16(an, f[j][nt], accn[nt], 0, 0, 0);
                accp[nt] = __builtin_amdgcn_mfma_f32_16x16x32_bf16(ap, f[j][nt], accp[nt], 0, 0, 0);
            }
        }
    }

    // epilogue: col = lane&15 within tile nt -> r = nt*16 + col
    float s3[3], h3[3];
#pragma unroll
    for (int nt = 0; nt < 3; ++nt) {
        f32x4 a = accn[nt];
        float m = fmaxf(fmaxf(a[0], a[1]), fmaxf(a[2], a[3]));
        m = fmaxf(m, __shfl_xor(m, 16));
        m = fmaxf(m, __shfl_xor(m, 32));   // max over the 16 neg rows
        float s = accp[nt][0];             // pos sim (all rows identical)
        s3[nt] = s;
        h3[nt] = fmaxf(m - s, 0.0f);
    }
    float mx = -1e30f;
#pragma unroll
    for (int nt = 0; nt < 3; ++nt)
        if (nt * 16 + lrow < RR) mx = fmaxf(mx, s3[nt]);
#pragma unroll
    for (int off = 1; off < 16; off <<= 1) mx = fmaxf(mx, __shfl_xor(mx, off));
    float den = 0.0f, num = 0.0f;
#pragma unroll
    for (int nt = 0; nt < 3; ++nt)
        if (nt * 16 + lrow < RR) {
            float e = __expf(s3[nt] - mx);
            den += e;
            num += e * h3[nt];
        }
#pragma unroll
    for (int off = 1; off < 16; off <<= 1) {
        den += __shfl_xor(den, off);
        num += __shfl_xor(num, off);
    }

    __shared__ float red[4];
    if (lane == 0) red[wv] = num / den;
    __syncthreads();
    if (tid == 0)
        atomicAdd(&ws[(t == 0) ? 0 : 1], red[0] + red[1] + red[2] + red[3]);
}

__global__ __launch_bounds__(64) void k_final(const float* __restrict__ ws,
                                              float* __restrict__ out) {
    if (threadIdx.x == 0) {
        const float obj = ws[0], attr = ws[1], rel = ws[2], comp = ws[3], sent = ws[4];
        out[0] = sent + 0.5f * comp + 0.5f * rel + 0.5f * attr + 0.5f * obj;
        out[1] = obj;
        out[2] = attr;
        out[3] = rel;
        out[4] = comp;
        out[5] = sent;
    }
}

extern "C" void kernel_launch(void* const* d_in, const int* in_sizes, int n_in,
                              void* d_out, int out_size, void* d_ws, size_t ws_size,
                              hipStream_t stream) {
    const float* img    = (const float*)d_in[0];
    const float* sent   = (const float*)d_in[1];
    const float* comp   = (const float*)d_in[2];
    const float* feat   = (const float*)d_in[3];
    const float* obj    = (const float*)d_in[4];
    const float* nobj   = (const float*)d_in[5];
    const float* attr   = (const float*)d_in[6];
    const float* nattrn = (const float*)d_in[7];
    const float* nattra = (const float*)d_in[8];
    const float* rel    = (const float*)d_in[9];
    const float* nrel   = (const float*)d_in[10];
    const int*   relidx = (const int*)d_in[11];
    float* ws  = (float*)d_ws;
    float* out = (float*)d_out;
    __bf16* wsf = (__bf16*)((char*)d_ws + WSF_OFF_BYTES);

    const bool usewsf = (ws_size >= WSF_BYTES);

    k_zero<<<dim3(1), dim3(64), 0, stream>>>(ws);
    k_diag<<<dim3(BB, 3), dim3(64), 0, stream>>>(img, sent, comp, rel, relidx, ws);
    k_contrastive<<<dim3(8, 8, 3), dim3(256), 0, stream>>>(img, sent, comp, rel, relidx, ws);
    k_globalrel<<<dim3(BB * PRR), dim3(64), 0, stream>>>(img, rel, nrel, ws);
    if (usewsf) {
        k_featcvt<<<dim3(BB, 3), dim3(256), 0, stream>>>(feat, wsf);
        k_local4<true><<<dim3(3, BB, 2), dim3(256), 0, stream>>>(feat, obj, attr, nobj, nattrn,
                                                                 nattra, wsf, ws);
    } else {
        k_local4<false><<<dim3(3, BB, 2), dim3(256), 0, stream>>>(feat, obj, attr, nobj, nattrn,
                                                                  nattra, wsf, ws);
    }
    k_final<<<dim3(1), dim3(64), 0, stream>>>(ws, out);
}

// Round 5
// 106.493 us; speedup vs baseline: 1.0367x; 1.0367x over previous
//
#include <hip/hip_runtime.h>

#define BB   128
#define DD   1024
#define RR   36
#define PP   8
#define NNEG 16
#define PRR  4

typedef __bf16 bf16x8 __attribute__((ext_vector_type(8)));
typedef float f32x4 __attribute__((ext_vector_type(4)));

// ws float layout: [0]=obj [1]=attr [2]=rel [3]=comp [4]=sent ; [16..400)=diag[3][128]
// byte 4096+: bf16 feat fragments [b][nt(3)][ks(32)][lane(64)][8]
#define WS_DIAG 16
#define WSF_OFF_BYTES 4096
#define WSF_PER_B (3 * 32 * 64 * 8)  // bf16 elems per b
#define WSF_BYTES ((size_t)WSF_OFF_BYTES + (size_t)BB * WSF_PER_B * 2)

__global__ __launch_bounds__(64) void k_zero(float* __restrict__ ws) {
    int t = threadIdx.x;
    if (t < 8) ws[t] = 0.0f;
}

__global__ __launch_bounds__(64) void k_diag(const float* __restrict__ img,
                                             const float* __restrict__ sent,
                                             const float* __restrict__ comp,
                                             const float* __restrict__ rel,
                                             const int*   __restrict__ relidx,
                                             float* __restrict__ ws) {
    const int i = blockIdx.x, t = blockIdx.y, lane = threadIdx.x;
    const float* x;
    if (t == 0)      x = sent + (size_t)i * DD;
    else if (t == 1) x = comp + (size_t)i * DD;
    else             x = rel + ((size_t)i * PRR + relidx[i]) * DD;
    const float* a = img + (size_t)i * DD;
    float acc = 0.0f;
#pragma unroll
    for (int k = 0; k < 4; ++k) {
        float4 va = *reinterpret_cast<const float4*>(a + lane * 4 + k * 256);
        float4 vb = *reinterpret_cast<const float4*>(x + lane * 4 + k * 256);
        acc += va.x * vb.x + va.y * vb.y + va.z * vb.z + va.w * vb.w;
    }
#pragma unroll
    for (int off = 32; off > 0; off >>= 1) acc += __shfl_down(acc, off);
    if (lane == 0) ws[WS_DIAG + t * BB + i] = acc;
}

// scores tile (16x16) per block; grid (8,8,3); 256 threads = 16x16
__global__ __launch_bounds__(256) void k_contrastive(const float* __restrict__ img,
                                                     const float* __restrict__ sent,
                                                     const float* __restrict__ comp,
                                                     const float* __restrict__ rel,
                                                     const int*   __restrict__ relidx,
                                                     float* __restrict__ ws) {
    const int t  = blockIdx.z;
    const int i0 = blockIdx.y * 16, j0 = blockIdx.x * 16;
    const int tid = threadIdx.x, ty = tid >> 4, tx = tid & 15;
    __shared__ float As[16][68];
    __shared__ float Bs[16][68];
    __shared__ float red[4];

    const int j_row = j0 + ty;
    const float* brow;
    if (t == 0)      brow = sent + (size_t)j_row * DD;
    else if (t == 1) brow = comp + (size_t)j_row * DD;
    else             brow = rel + ((size_t)j_row * PRR + relidx[j_row]) * DD;
    const float* arow = img + (size_t)(i0 + ty) * DD;

    float acc = 0.0f;
    for (int kc = 0; kc < DD; kc += 64) {
        __syncthreads();
        float4 va = *reinterpret_cast<const float4*>(arow + kc + tx * 4);
        float4 vb = *reinterpret_cast<const float4*>(brow + kc + tx * 4);
        *reinterpret_cast<float4*>(&As[ty][tx * 4]) = va;
        *reinterpret_cast<float4*>(&Bs[ty][tx * 4]) = vb;
        __syncthreads();
#pragma unroll 8
        for (int d = 0; d < 64; ++d)
            acc += As[ty][d] * Bs[tx][d];
    }

    const int i = i0 + ty, j = j0 + tx;
    const float diag_i = ws[WS_DIAG + t * BB + i];
    const float diag_j = ws[WS_DIAG + t * BB + j];
    float contrib = 0.0f;
    if (i != j) {
        contrib = fmaxf(acc - diag_i, 0.0f);             // cost_s
        if (t < 2) contrib += fmaxf(acc - diag_j, 0.0f); // cost_im (not for rel)
    }
#pragma unroll
    for (int off = 32; off > 0; off >>= 1) contrib += __shfl_down(contrib, off);
    if ((tid & 63) == 0) red[tid >> 6] = contrib;
    __syncthreads();
    if (tid == 0) {
        const int slot = (t == 0) ? 4 : (t == 1) ? 3 : 2;  // sent/comp/rel
        atomicAdd(&ws[slot], red[0] + red[1] + red[2] + red[3]);
    }
}

// global_loss for rel: grid(512) = (b,p); 64 threads
__global__ __launch_bounds__(64) void k_globalrel(const float* __restrict__ img,
                                                  const float* __restrict__ rel,
                                                  const float* __restrict__ negrel,
                                                  float* __restrict__ ws) {
    const int blk = blockIdx.x, b = blk >> 2, p = blk & 3;
    const int lane = threadIdx.x;
    const float* a = img + (size_t)b * DD;
    float4 ir[4];
#pragma unroll
    for (int k = 0; k < 4; ++k)
        ir[k] = *reinterpret_cast<const float4*>(a + lane * 4 + k * 256);

    auto dotv = [&](const float* __restrict__ v) -> float {
        float acc = 0.0f;
#pragma unroll
        for (int k = 0; k < 4; ++k) {
            float4 w = *reinterpret_cast<const float4*>(v + lane * 4 + k * 256);
            acc += ir[k].x * w.x + ir[k].y * w.y + ir[k].z * w.z + ir[k].w * w.w;
        }
#pragma unroll
        for (int off = 32; off > 0; off >>= 1) acc += __shfl_xor(acc, off);
        return acc;
    };

    float pos = dotv(rel + ((size_t)b * PRR + p) * DD);
    float mx = -1e30f;
    const float* nb = negrel + ((size_t)b * PRR + p) * NNEG * DD;
    for (int n = 0; n < NNEG; ++n) mx = fmaxf(mx, dotv(nb + (size_t)n * DD));
    if (lane == 0) atomicAdd(&ws[2], fmaxf(mx - pos, 0.0f));
}

// Pre-convert feat to bf16 in MFMA B-fragment layout: [b][nt][ks][lane]x8,
// where lane encodes (col r = nt*16 + (lane&15), k-sub (lane>>4)*8).
__global__ __launch_bounds__(256) void k_featcvt(const float* __restrict__ feat,
                                                 __bf16* __restrict__ wsf) {
    const int b = blockIdx.x, nt = blockIdx.y, tid = threadIdx.x;
    const float* fb = feat + (size_t)b * RR * DD;
    __bf16* ob = wsf + (size_t)b * WSF_PER_B + (size_t)nt * 32 * 64 * 8;
    for (int i = tid; i < 32 * 64; i += 256) {
        const int ks = i >> 6, lane = i & 63;
        const int r = nt * 16 + (lane & 15);
        const int k0 = ks * 32 + (lane >> 4) * 8;
        bf16x8 w;
        if (r < RR) {
            float4 v0 = *reinterpret_cast<const float4*>(fb + (size_t)r * DD + k0);
            float4 v1 = *reinterpret_cast<const float4*>(fb + (size_t)r * DD + k0 + 4);
            w[0] = (__bf16)v0.x; w[1] = (__bf16)v0.y; w[2] = (__bf16)v0.z; w[3] = (__bf16)v0.w;
            w[4] = (__bf16)v1.x; w[5] = (__bf16)v1.y; w[6] = (__bf16)v1.z; w[7] = (__bf16)v1.w;
        } else {
#pragma unroll
            for (int j = 0; j < 8; ++j) w[j] = (__bf16)0.0f;
        }
        *reinterpret_cast<bf16x8*>(ob + (size_t)i * 8) = w;
    }
}

// local_loss via bf16 MFMA, split-K x2 for TLP.
// grid (3 t, 128 b, 4 p-pair); 256 threads = 4 waves = (2 p) x (2 kh).
// Wave (pp,kh) computes partial scores over K in [kh*512, kh*512+512);
// kh=1 waves hand their partials to kh=0 waves via LDS; kh=0 runs epilogue.
template <bool WSFEAT>
__global__ __launch_bounds__(256) void k_local5(const float* __restrict__ feat,
                                                const float* __restrict__ obj,
                                                const float* __restrict__ attr,
                                                const float* __restrict__ nobj,
                                                const float* __restrict__ nattrn,
                                                const float* __restrict__ nattra,
                                                const __bf16* __restrict__ wsf,
                                                float* __restrict__ ws) {
    const int t = blockIdx.x;   // 0:obj 1:attr(n) 2:attr(a)
    const int b = blockIdx.y;
    const int tid = threadIdx.x;
    const int wv = tid >> 6;
    const int pp = wv >> 1;               // p within the pair
    const int kh = wv & 1;                // K-half
    const int p = blockIdx.z * 2 + pp;
    const int lane = tid & 63;
    const int lrow = lane & 15;
    const int kgq = lane >> 4;            // k-sub-group, *8 for element offset
    const int ksbase = kh * 16;           // 16 ks-steps of 32 per half

    const float* pos = (t == 0) ? obj : attr;
    const float* neg = (t == 0) ? nobj : (t == 1) ? nattrn : nattra;
    const float* posb = pos + ((size_t)b * PP + p) * DD + kgq * 8;
    const float* negb = neg + ((size_t)(b * PP + p) * NNEG + lrow) * DD + kgq * 8;
    const float* fb   = feat + (size_t)b * RR * DD;
    const __bf16* wfb = wsf + (size_t)b * WSF_PER_B + (size_t)lane * 8;

    f32x4 accn[3], accp[3];
#pragma unroll
    for (int nt = 0; nt < 3; ++nt) {
        accn[nt] = (f32x4){0.f, 0.f, 0.f, 0.f};
        accp[nt] = (f32x4){0.f, 0.f, 0.f, 0.f};
    }

    auto LOAD = [&](int ksl, float4& n0, float4& n1, float4& p0, float4& p1, bf16x8* f) {
        const int ks = ksbase + ksl;
        const float* np = negb + ks * 32;
        n0 = *reinterpret_cast<const float4*>(np);
        n1 = *reinterpret_cast<const float4*>(np + 4);
        const float* pp_ = posb + ks * 32;
        p0 = *reinterpret_cast<const float4*>(pp_);
        p1 = *reinterpret_cast<const float4*>(pp_ + 4);
        if (WSFEAT) {
#pragma unroll
            for (int nt = 0; nt < 3; ++nt)
                f[nt] = *reinterpret_cast<const bf16x8*>(wfb + ((size_t)(nt * 32 + ks)) * 512);
        } else {
#pragma unroll
            for (int nt = 0; nt < 3; ++nt) {
                const int r = nt * 16 + lrow;
                if (r < RR) {
                    const float* fp = fb + (size_t)r * DD + ks * 32 + kgq * 8;
                    float4 v0 = *reinterpret_cast<const float4*>(fp);
                    float4 v1 = *reinterpret_cast<const float4*>(fp + 4);
                    f[nt][0] = (__bf16)v0.x; f[nt][1] = (__bf16)v0.y;
                    f[nt][2] = (__bf16)v0.z; f[nt][3] = (__bf16)v0.w;
                    f[nt][4] = (__bf16)v1.x; f[nt][5] = (__bf16)v1.y;
                    f[nt][6] = (__bf16)v1.z; f[nt][7] = (__bf16)v1.w;
                } else {
#pragma unroll
                    for (int j = 0; j < 8; ++j) f[nt][j] = (__bf16)0.0f;
                }
            }
        }
    };

    float4 cn0, cn1, cp0, cp1;
    bf16x8 cf[3];
    LOAD(0, cn0, cn1, cp0, cp1, cf);

#pragma unroll
    for (int ksl = 0; ksl < 16; ++ksl) {
        float4 nn0 = cn0, nn1 = cn1, np0 = cp0, np1 = cp1;
        bf16x8 nf[3] = {cf[0], cf[1], cf[2]};
        if (ksl + 1 < 16) LOAD(ksl + 1, nn0, nn1, np0, np1, nf);

        bf16x8 an, ap;
        an[0] = (__bf16)cn0.x; an[1] = (__bf16)cn0.y; an[2] = (__bf16)cn0.z; an[3] = (__bf16)cn0.w;
        an[4] = (__bf16)cn1.x; an[5] = (__bf16)cn1.y; an[6] = (__bf16)cn1.z; an[7] = (__bf16)cn1.w;
        ap[0] = (__bf16)cp0.x; ap[1] = (__bf16)cp0.y; ap[2] = (__bf16)cp0.z; ap[3] = (__bf16)cp0.w;
        ap[4] = (__bf16)cp1.x; ap[5] = (__bf16)cp1.y; ap[6] = (__bf16)cp1.z; ap[7] = (__bf16)cp1.w;

#pragma unroll
        for (int nt = 0; nt < 3; ++nt) {
            accn[nt] = __builtin_amdgcn_mfma_f32_16x16x32_bf16(an, cf[nt], accn[nt], 0, 0, 0);
            accp[nt] = __builtin_amdgcn_mfma_f32_16x16x32_bf16(ap, cf[nt], accp[nt], 0, 0, 0);
        }
        cn0 = nn0; cn1 = nn1; cp0 = np0; cp1 = np1;
        cf[0] = nf[0]; cf[1] = nf[1]; cf[2] = nf[2];
    }

    // cross-half combine: kh=1 waves publish 15 floats/lane, kh=0 waves sum.
    __shared__ float X[2][64][17];
    __shared__ float red[2];
    if (kh == 1) {
#pragma unroll
        for (int nt = 0; nt < 3; ++nt) {
            X[pp][lane][nt * 4 + 0] = accn[nt][0];
            X[pp][lane][nt * 4 + 1] = accn[nt][1];
            X[pp][lane][nt * 4 + 2] = accn[nt][2];
            X[pp][lane][nt * 4 + 3] = accn[nt][3];
            X[pp][lane][12 + nt]    = accp[nt][0];
        }
    }
    __syncthreads();
    if (kh == 0) {
#pragma unroll
        for (int nt = 0; nt < 3; ++nt) {
            accn[nt][0] += X[pp][lane][nt * 4 + 0];
            accn[nt][1] += X[pp][lane][nt * 4 + 1];
            accn[nt][2] += X[pp][lane][nt * 4 + 2];
            accn[nt][3] += X[pp][lane][nt * 4 + 3];
            accp[nt][0] += X[pp][lane][12 + nt];
        }

        // epilogue: col = lane&15 within tile nt -> r = nt*16 + col
        float s3[3], h3[3];
#pragma unroll
        for (int nt = 0; nt < 3; ++nt) {
            f32x4 a = accn[nt];
            float m = fmaxf(fmaxf(a[0], a[1]), fmaxf(a[2], a[3]));
            m = fmaxf(m, __shfl_xor(m, 16));
            m = fmaxf(m, __shfl_xor(m, 32));   // max over the 16 neg rows
            float s = accp[nt][0];             // pos sim
            s3[nt] = s;
            h3[nt] = fmaxf(m - s, 0.0f);
        }
        float mx = -1e30f;
#pragma unroll
        for (int nt = 0; nt < 3; ++nt)
            if (nt * 16 + lrow < RR) mx = fmaxf(mx, s3[nt]);
#pragma unroll
        for (int off = 1; off < 16; off <<= 1) mx = fmaxf(mx, __shfl_xor(mx, off));
        float den = 0.0f, num = 0.0f;
#pragma unroll
        for (int nt = 0; nt < 3; ++nt)
            if (nt * 16 + lrow < RR) {
                float e = __expf(s3[nt] - mx);
                den += e;
                num += e * h3[nt];
            }
#pragma unroll
        for (int off = 1; off < 16; off <<= 1) {
            den += __shfl_xor(den, off);
            num += __shfl_xor(num, off);
        }
        if (lane == 0) red[pp] = num / den;
    }
    __syncthreads();
    if (tid == 0)
        atomicAdd(&ws[(t == 0) ? 0 : 1], red[0] + red[1]);
}

__global__ __launch_bounds__(64) void k_final(const float* __restrict__ ws,
                                              float* __restrict__ out) {
    if (threadIdx.x == 0) {
        const float obj = ws[0], attr = ws[1], rel = ws[2], comp = ws[3], sent = ws[4];
        out[0] = sent + 0.5f * comp + 0.5f * rel + 0.5f * attr + 0.5f * obj;
        out[1] = obj;
        out[2] = attr;
        out[3] = rel;
        out[4] = comp;
        out[5] = sent;
    }
}

extern "C" void kernel_launch(void* const* d_in, const int* in_sizes, int n_in,
                              void* d_out, int out_size, void* d_ws, size_t ws_size,
                              hipStream_t stream) {
    const float* img    = (const float*)d_in[0];
    const float* sent   = (const float*)d_in[1];
    const float* comp   = (const float*)d_in[2];
    const float* feat   = (const float*)d_in[3];
    const float* obj    = (const float*)d_in[4];
    const float* nobj   = (const float*)d_in[5];
    const float* attr   = (const float*)d_in[6];
    const float* nattrn = (const float*)d_in[7];
    const float* nattra = (const float*)d_in[8];
    const float* rel    = (const float*)d_in[9];
    const float* nrel   = (const float*)d_in[10];
    const int*   relidx = (const int*)d_in[11];
    float* ws  = (float*)d_ws;
    float* out = (float*)d_out;
    __bf16* wsf = (__bf16*)((char*)d_ws + WSF_OFF_BYTES);

    const bool usewsf = (ws_size >= WSF_BYTES);

    k_zero<<<dim3(1), dim3(64), 0, stream>>>(ws);
    k_diag<<<dim3(BB, 3), dim3(64), 0, stream>>>(img, sent, comp, rel, relidx, ws);
    k_contrastive<<<dim3(8, 8, 3), dim3(256), 0, stream>>>(img, sent, comp, rel, relidx, ws);
    k_globalrel<<<dim3(BB * PRR), dim3(64), 0, stream>>>(img, rel, nrel, ws);
    if (usewsf) {
        k_featcvt<<<dim3(BB, 3), dim3(256), 0, stream>>>(feat, wsf);
        k_local5<true><<<dim3(3, BB, 4), dim3(256), 0, stream>>>(feat, obj, attr, nobj, nattrn,
                                                                 nattra, wsf, ws);
    } else {
        k_local5<false><<<dim3(3, BB, 4), dim3(256), 0, stream>>>(feat, obj, attr, nobj, nattrn,
                                                                  nattra, wsf, ws);
    }
    k_final<<<dim3(1), dim3(64), 0, stream>>>(ws, out);
}